// Round 1
// baseline (726.001 us; speedup 1.0000x reference)
//
#include <hip/hip_runtime.h>
#include <math.h>

// Problem constants (fixed by setup_inputs): B=16, T_max=128, S_max=64, V=1024.
#define Bc 16
#define TM 128
#define SMAX 64
#define VV 1024
#define NEGF (-1e30f)
#define CELLS (Bc * TM * (SMAX + 1))   // 133120 cells/rows

typedef float f32x4 __attribute__((ext_vector_type(4)));

__device__ __forceinline__ float wave_sum64(float v) {
  #pragma unroll
  for (int o = 32; o > 0; o >>= 1) v += __shfl_down(v, o);
  return __shfl(v, 0);
}
// Fast logaddexp: safe for NEG sentinels (-1e30). d<=0 so 1+exp(d) in (1,2].
__device__ __forceinline__ float logaddexp_f(float a, float b) {
  float m = fmaxf(a, b);
  float d = fminf(a, b) - m;
  return m + __logf(1.0f + __expf(d));
}

// ---------------- Phase 1: per-row logsumexp + blank/label gather ----------
// Each 64-lane wave owns RPW consecutive cells. Batch offsets come from a
// one-time 16-lane shuffle prefix scan (no serial per-wave load loop).
// Double-buffered pair pipeline: while computing pair i, pair i+1's eight
// 16B loads are in flight. Fully unrolled => all buffer indices static.
#define RPW 16
#define NPAIR (RPW / 2)

__global__ __launch_bounds__(256, 4) void rnnt_lp_kernel(
    const float* __restrict__ acts, const int* __restrict__ labels,
    const int* __restrict__ Tlen, const int* __restrict__ Slen,
    float* __restrict__ blank_lp, float* __restrict__ label_lp)
{
  const int lane = threadIdx.x & 63;
  const int wv   = threadIdx.x >> 6;
  const int wave = blockIdx.x * 4 + wv;
  const int cbase = wave * RPW;
  if (cbase >= CELLS) return;

  // One-time: lane i (i<16) holds T_i, S_i, and the exclusive prefix of
  // sizes (row offset of batch i). Lanes 16..63 hold garbage but are never
  // read: all later __shfl sources are lanes 0..15.
  const int bidx = lane & 15;
  const int Tb_l = Tlen[bidx];
  const int Sb_l = Slen[bidx];
  const int sz   = Tb_l * (Sb_l + 1);
  int incl = sz;
  #pragma unroll
  for (int o = 1; o < 16; o <<= 1) {
    int u = __shfl_up(incl, o);
    if (bidx >= o) incl += u;
  }
  const int excl = incl - sz;

  struct Geo {
    int lab_idx;   // index into label_lp (valid when s < SMAX)
    int s, Sb, lab;
    long long row; // packed acts row (dead after issue)
    bool val;
  };

  auto geo = [&](int cell) {
    Geo g;
    const int b   = cell / (TM * (SMAX + 1));
    const int rem = cell - b * (TM * (SMAX + 1));
    const int t   = rem / (SMAX + 1);
    g.s = rem - t * (SMAX + 1);
    const int Tb = __shfl(Tb_l, b);
    g.Sb = __shfl(Sb_l, b);
    const int off = __shfl(excl, b);
    g.row = (long long)off + (long long)t * (g.Sb + 1) + g.s;
    g.val = (t < Tb) && (g.s <= g.Sb);
    g.lab_idx = (b * TM + t) * SMAX + g.s;
    // prefetch the label with the row loads (hides L2 latency)
    g.lab = (g.val && g.s < g.Sb) ? labels[b * SMAX + g.s] : -1;
    return g;
  };

  auto issue = [&](const Geo& g, f32x4* x) {
    if (g.val) {
      const f32x4* rp = (const f32x4*)(acts + g.row * (long long)VV) + lane;
      x[0] = rp[0];
      x[1] = rp[64];
      x[2] = rp[128];
      x[3] = rp[192];
    }
  };

  auto compute = [&](int cell, const Geo& g, const f32x4* x) {
    if (!g.val) {
      if (lane == 0) {
        blank_lp[cell] = NEGF;
        if (g.s < SMAX) label_lp[g.lab_idx] = NEGF;
      }
      return;
    }
    float p = 0.0f;
    #pragma unroll
    for (int q = 0; q < 4; ++q)
      p += __expf(x[q].x) + __expf(x[q].y) + __expf(x[q].z) + __expf(x[q].w);
    const float lse = __logf(wave_sum64(p));
    if (g.s < g.Sb) {
      // wave-uniform label -> uniform (vec#, component, src lane) select
      const int f    = g.lab >> 2;
      const int comp = g.lab & 3;
      const int src  = f & 63;
      const int j    = f >> 6;
      f32x4 xx = (j == 0) ? x[0] : (j == 1) ? x[1] : (j == 2) ? x[2] : x[3];
      float v = (comp == 0) ? xx.x : (comp == 1) ? xx.y : (comp == 2) ? xx.z : xx.w;
      v = __shfl(v, src);
      if (lane == 0) label_lp[g.lab_idx] = v - lse;
    } else if (g.s < SMAX) {
      if (lane == 0) label_lp[g.lab_idx] = NEGF;
    }
    if (lane == 0) blank_lp[cell] = x[0].x - lse;  // blank = elem 0 (lane 0)
  };

  f32x4 xb[2][2][4];   // [ping][row-in-pair][vec4] = 64 VGPRs of data
  Geo   gb[2][2];

  gb[0][0] = geo(cbase + 0);
  gb[0][1] = geo(cbase + 1);
  issue(gb[0][0], xb[0][0]);
  issue(gb[0][1], xb[0][1]);

  #pragma unroll
  for (int i = 0; i < NPAIR; ++i) {
    const int cur = i & 1, nxt = cur ^ 1;
    if (i + 1 < NPAIR) {
      gb[nxt][0] = geo(cbase + 2 * i + 2);
      gb[nxt][1] = geo(cbase + 2 * i + 3);
      issue(gb[nxt][0], xb[nxt][0]);
      issue(gb[nxt][1], xb[nxt][1]);
    }
    compute(cbase + 2 * i + 0, gb[cur][0], xb[cur][0]);
    compute(cbase + 2 * i + 1, gb[cur][1], xb[cur][1]);
  }
}

// ---------------- Phase 2: alpha recurrence, one block per batch ----------
// 256 threads stage the 66 KB of log-probs into LDS (4x fewer iterations
// than the old 64-thread version), then wave 0 runs the T-step recurrence
// with in-register alpha: lane holds alpha[lane]; alpha[64] in a_hi.
__global__ __launch_bounds__(256) void rnnt_alpha_kernel(
    const float* __restrict__ blank_lp, const float* __restrict__ label_lp,
    const int* __restrict__ Tlen, const int* __restrict__ Slen,
    float* __restrict__ out)
{
  __shared__ __align__(16) float sb[TM * (SMAX + 1)];  // 8320 floats
  __shared__ __align__(16) float sl[TM * SMAX];        // 8192 floats
  const int b = blockIdx.x;
  const int tid = threadIdx.x;

  const float* gb = blank_lp + (size_t)b * TM * (SMAX + 1);
  const float* gl = label_lp + (size_t)b * TM * SMAX;
  for (int i = tid * 4; i < TM * (SMAX + 1); i += 256 * 4)
    *(float4*)&sb[i] = *(const float4*)&gb[i];
  for (int i = tid * 4; i < TM * SMAX; i += 256 * 4)
    *(float4*)&sl[i] = *(const float4*)&gl[i];
  __syncthreads();
  if (tid >= 64) return;

  const int lane = tid;
  const int Tb = Tlen[b], Sb = Slen[b];
  float a    = (lane == 0) ? 0.0f : NEGF;  // alpha[lane], lane in [0,64)
  float a_hi = NEGF;                       // alpha[64], uniform on all lanes

  for (int t = 0; t < Tb; ++t) {
    const float blp      = sb[t * (SMAX + 1) + lane];
    const float llp_prev = (lane >= 1) ? sl[t * SMAX + lane - 1] : NEGF;
    const float blp64    = sb[t * (SMAX + 1) + 64];  // broadcast
    const float llp63    = sl[t * SMAX + 63];        // broadcast
    const float a_prev   = __shfl_up(a, 1);
    const float a63      = __shfl(a, 63);            // uniform
    const float newv = logaddexp_f(a + blp,
                                   (lane >= 1) ? (a_prev + llp_prev) : NEGF);
    const float new_hi = logaddexp_f(a_hi + blp64, a63 + llp63);
    a = newv;
    a_hi = new_hi;
  }

  const float via_shfl = __shfl(a, Sb & 63);  // executed by all lanes
  const float aS = (Sb < 64) ? via_shfl : a_hi;
  if (lane == 0) out[b] = -aS;
}

extern "C" void kernel_launch(void* const* d_in, const int* in_sizes, int n_in,
                              void* d_out, int out_size, void* d_ws, size_t ws_size,
                              hipStream_t stream) {
  const float* acts  = (const float*)d_in[0];
  const int* labels  = (const int*)d_in[1];
  const int* Tlen    = (const int*)d_in[2];
  const int* Slen    = (const int*)d_in[3];
  float* out = (float*)d_out;

  float* blank_lp = (float*)d_ws;                       // B*TM*(SMAX+1) floats
  float* label_lp = blank_lp + Bc * TM * (SMAX + 1);    // B*TM*SMAX floats

  const int waves_total  = (CELLS + RPW - 1) / RPW;     // 8320
  const int blocks       = (waves_total + 3) / 4;       // 2080
  rnnt_lp_kernel<<<blocks, 256, 0, stream>>>(
      acts, labels, Tlen, Slen, blank_lp, label_lp);
  rnnt_alpha_kernel<<<Bc, 256, 0, stream>>>(
      blank_lp, label_lp, Tlen, Slen, out);
}

// Round 3
// 716.185 us; speedup vs baseline: 1.0137x; 1.0137x over previous
//
#include <hip/hip_runtime.h>
#include <math.h>

// Problem constants (fixed by setup_inputs): B=16, T_max=128, S_max=64, V=1024.
#define Bc 16
#define TM 128
#define SMAX 64
#define VV 1024
#define NEGF (-1e30f)
#define CELLS (Bc * TM * (SMAX + 1))   // 133120 cells/rows

typedef float f32x4 __attribute__((ext_vector_type(4)));

// Fast logaddexp: safe for NEG sentinels (-1e30). d<=0 so 1+exp(d) in (1,2].
__device__ __forceinline__ float logaddexp_f(float a, float b) {
  float m = fmaxf(a, b);
  float d = fminf(a, b) - m;
  return m + __logf(1.0f + __expf(d));
}

// ---------------- Phase 1: per-row logsumexp + blank/label gather ----------
// 4 rows per 64-lane wave. One-time 16-lane shuffle prefix scan for batch
// offsets (no serial load loop). All 16 row-loads (256 B/lane) issued in a
// single burst; the four wave-wide reductions run as interleaved shfl_xor
// butterflies so the 6-step dependency chain is amortized 4x. No double
// buffering, no structs, no launch_bounds reg cap => no spills.
#define RPG 4   // rows per wave

__global__ __launch_bounds__(256) void rnnt_lp_kernel(
    const float* __restrict__ acts, const int* __restrict__ labels,
    const int* __restrict__ Tlen, const int* __restrict__ Slen,
    float* __restrict__ blank_lp, float* __restrict__ label_lp)
{
  const int lane = threadIdx.x & 63;
  const int wv   = threadIdx.x >> 6;
  const int grp  = blockIdx.x * 4 + wv;
  const int cell0 = grp * RPG;
  if (cell0 >= CELLS) return;

  // One-time: lane i (i<16) holds T_i, S_i, and the exclusive prefix of
  // sizes (row offset of batch i). Lanes 16..63 hold garbage but are never
  // read: all later __shfl sources are lanes 0..15.
  const int bidx = lane & 15;
  const int Tb_l = Tlen[bidx];
  const int Sb_l = Slen[bidx];
  const int sz   = Tb_l * (Sb_l + 1);
  int incl = sz;
  #pragma unroll
  for (int o = 1; o < 16; o <<= 1) {
    int u = __shfl_up(incl, o);
    if (bidx >= o) incl += u;
  }
  const int excl = incl - sz;

  int s_[RPG], Sb_[RPG], lab_[RPG], labidx_[RPG];
  bool val_[RPG];
  unsigned off_[RPG];           // byte offset of row base (row*4096 < 2^30)
  f32x4 x[RPG][4];

  #pragma unroll
  for (int k = 0; k < RPG; ++k) {
    const int cell = cell0 + k;
    const int b   = cell / (TM * (SMAX + 1));
    const int rem = cell - b * (TM * (SMAX + 1));
    const int t   = rem / (SMAX + 1);
    const int s   = rem - t * (SMAX + 1);
    const int Tb  = __shfl(Tb_l, b);
    const int Sb  = __shfl(Sb_l, b);
    const int rb  = __shfl(excl, b);       // batch row offset
    s_[k] = s; Sb_[k] = Sb;
    labidx_[k] = (b * TM + t) * SMAX + s;  // valid when s < SMAX
    val_[k] = (t < Tb) && (s <= Sb);
    const unsigned row = (unsigned)rb + (unsigned)t * (unsigned)(Sb + 1) + (unsigned)s;
    off_[k] = row * (unsigned)(VV * 4);
    // prefetch the label with the row loads (hides L2 latency)
    lab_[k] = (val_[k] && s < Sb) ? labels[b * SMAX + s] : -1;
  }

  // ---- single burst: 16 x 16B loads in flight ----
  #pragma unroll
  for (int k = 0; k < RPG; ++k) {
    if (val_[k]) {
      const f32x4* rp = (const f32x4*)((const char*)acts + off_[k]) + lane;
      x[k][0] = rp[0];
      x[k][1] = rp[64];
      x[k][2] = rp[128];
      x[k][3] = rp[192];
    }
  }

  // ---- per-lane partial sums (64 exps, independent) ----
  float p[RPG];
  #pragma unroll
  for (int k = 0; k < RPG; ++k) {
    float q = 0.0f;
    #pragma unroll
    for (int j = 0; j < 4; ++j)
      q += __expf(x[k][j].x) + __expf(x[k][j].y) +
           __expf(x[k][j].z) + __expf(x[k][j].w);
    p[k] = q;
  }

  // ---- 4 interleaved xor-butterflies: all lanes end with the row sums ----
  #pragma unroll
  for (int o = 1; o < 64; o <<= 1) {
    #pragma unroll
    for (int k = 0; k < RPG; ++k) p[k] += __shfl_xor(p[k], o);
  }

  // ---- epilogue: blank/label log-probs ----
  #pragma unroll
  for (int k = 0; k < RPG; ++k) {
    const int cell = cell0 + k;
    if (!val_[k]) {
      if (lane == 0) {
        blank_lp[cell] = NEGF;
        if (s_[k] < SMAX) label_lp[labidx_[k]] = NEGF;
      }
      continue;
    }
    const float lse = __logf(p[k]);
    if (s_[k] < Sb_[k]) {
      // wave-uniform label -> uniform (vec#, component, src lane) select
      const int f    = lab_[k] >> 2;
      const int comp = lab_[k] & 3;
      const int src  = f & 63;
      const int j    = f >> 6;
      f32x4 xx = (j == 0) ? x[k][0] : (j == 1) ? x[k][1] : (j == 2) ? x[k][2] : x[k][3];
      float v = (comp == 0) ? xx.x : (comp == 1) ? xx.y : (comp == 2) ? xx.z : xx.w;
      v = __shfl(v, src);
      if (lane == 0) label_lp[labidx_[k]] = v - lse;
    } else if (s_[k] < SMAX) {
      if (lane == 0) label_lp[labidx_[k]] = NEGF;
    }
    if (lane == 0) blank_lp[cell] = x[k][0].x - lse;  // blank = elem 0 (lane 0)
  }
}

// ---------------- Phase 2: alpha recurrence, one block per batch ----------
// 256 threads stage the 66 KB of log-probs into LDS, then wave 0 runs the
// T-step recurrence with in-register alpha: lane holds alpha[lane];
// alpha[64] replicated uniformly in a_hi. No __syncthreads in the time loop.
__global__ __launch_bounds__(256) void rnnt_alpha_kernel(
    const float* __restrict__ blank_lp, const float* __restrict__ label_lp,
    const int* __restrict__ Tlen, const int* __restrict__ Slen,
    float* __restrict__ out)
{
  __shared__ __align__(16) float sb[TM * (SMAX + 1)];  // 8320 floats
  __shared__ __align__(16) float sl[TM * SMAX];        // 8192 floats
  const int b = blockIdx.x;
  const int tid = threadIdx.x;

  const float* gb = blank_lp + (size_t)b * TM * (SMAX + 1);
  const float* gl = label_lp + (size_t)b * TM * SMAX;
  for (int i = tid * 4; i < TM * (SMAX + 1); i += 256 * 4)
    *(float4*)&sb[i] = *(const float4*)&gb[i];
  for (int i = tid * 4; i < TM * SMAX; i += 256 * 4)
    *(float4*)&sl[i] = *(const float4*)&gl[i];
  __syncthreads();
  if (tid >= 64) return;

  const int lane = tid;
  const int Tb = Tlen[b], Sb = Slen[b];
  float a    = (lane == 0) ? 0.0f : NEGF;  // alpha[lane], lane in [0,64)
  float a_hi = NEGF;                       // alpha[64], uniform on all lanes

  for (int t = 0; t < Tb; ++t) {
    const float blp      = sb[t * (SMAX + 1) + lane];
    const float llp_prev = (lane >= 1) ? sl[t * SMAX + lane - 1] : NEGF;
    const float blp64    = sb[t * (SMAX + 1) + 64];  // broadcast
    const float llp63    = sl[t * SMAX + 63];        // broadcast
    const float a_prev   = __shfl_up(a, 1);
    const float a63      = __shfl(a, 63);            // uniform
    const float newv = logaddexp_f(a + blp,
                                   (lane >= 1) ? (a_prev + llp_prev) : NEGF);
    const float new_hi = logaddexp_f(a_hi + blp64, a63 + llp63);
    a = newv;
    a_hi = new_hi;
  }

  const float via_shfl = __shfl(a, Sb & 63);  // executed by all lanes
  const float aS = (Sb < 64) ? via_shfl : a_hi;
  if (lane == 0) out[b] = -aS;
}

extern "C" void kernel_launch(void* const* d_in, const int* in_sizes, int n_in,
                              void* d_out, int out_size, void* d_ws, size_t ws_size,
                              hipStream_t stream) {
  const float* acts  = (const float*)d_in[0];
  const int* labels  = (const int*)d_in[1];
  const int* Tlen    = (const int*)d_in[2];
  const int* Slen    = (const int*)d_in[3];
  float* out = (float*)d_out;

  float* blank_lp = (float*)d_ws;                       // B*TM*(SMAX+1) floats
  float* label_lp = blank_lp + Bc * TM * (SMAX + 1);    // B*TM*SMAX floats

  const int groups = (CELLS + RPG - 1) / RPG;           // 33280 waves
  const int blocks = (groups + 3) / 4;                  // 8320 blocks
  rnnt_lp_kernel<<<blocks, 256, 0, stream>>>(
      acts, labels, Tlen, Slen, blank_lp, label_lp);
  rnnt_alpha_kernel<<<Bc, 256, 0, stream>>>(
      blank_lp, label_lp, Tlen, Slen, out);
}

// Round 4
// 684.861 us; speedup vs baseline: 1.0601x; 1.0457x over previous
//
#include <hip/hip_runtime.h>
#include <math.h>

// Problem constants (fixed by setup_inputs): B=16, T_max=128, S_max=64, V=1024.
#define Bc 16
#define TM 128
#define SMAX 64
#define VV 1024
#define NEGF (-1e30f)
#define CELLS (Bc * TM * (SMAX + 1))   // 133120 cells/rows
#define NPAIRS (CELLS / 2)             // 66560 pairs of rows
#define LPBLOCKS 2048
#define NWAVES (LPBLOCKS * 4)          // 8192 persistent waves

typedef float f32x4 __attribute__((ext_vector_type(4)));

// Fast logaddexp: safe for NEG sentinels (-1e30). d<=0 so 1+exp(d) in (1,2].
__device__ __forceinline__ float logaddexp_f(float a, float b) {
  float m = fmaxf(a, b);
  float d = fminf(a, b) - m;
  return m + __logf(1.0f + __expf(d));
}

// ---------------- Phase 1: per-row logsumexp + blank/label gather ----------
// Persistent grid-stride waves, register ping-pong pipeline: while pair P's
// 32 exps + butterfly reduce run, pair P+stride's eight 16B nontemporal
// loads are in flight. Scalar-only rotation (named bufA/bufB, all indices
// static => no scratch). Nontemporal: acts is a 520 MiB stream-once input;
// bypassing L3 allocation avoids thrashing the 256 MiB LLC.
struct RowG {
  int s, Sb, lab, labidx;
  unsigned off;   // byte offset of row base (row*4096 < 2^30)
  bool val;
};

__global__ __launch_bounds__(256) void rnnt_lp_kernel(
    const float* __restrict__ acts, const int* __restrict__ labels,
    const int* __restrict__ Tlen, const int* __restrict__ Slen,
    float* __restrict__ blank_lp, float* __restrict__ label_lp)
{
  const int lane = threadIdx.x & 63;
  const int wv   = threadIdx.x >> 6;
  const int wave = blockIdx.x * 4 + wv;

  // One-time: lane i (i<16) holds T_i, S_i, and the exclusive prefix of
  // sizes (row offset of batch i). Lanes 16..63 hold garbage but are never
  // read: all later __shfl sources are lanes 0..15.
  const int bidx = lane & 15;
  const int Tb_l = Tlen[bidx];
  const int Sb_l = Slen[bidx];
  const int sz   = Tb_l * (Sb_l + 1);
  int incl = sz;
  #pragma unroll
  for (int o = 1; o < 16; o <<= 1) {
    int u = __shfl_up(incl, o);
    if (bidx >= o) incl += u;
  }
  const int excl = incl - sz;

  auto geo = [&](int cell, RowG& g) {
    const int b   = cell / (TM * (SMAX + 1));
    const int rem = cell - b * (TM * (SMAX + 1));
    const int t   = rem / (SMAX + 1);
    g.s = rem - t * (SMAX + 1);
    const int Tb = __shfl(Tb_l, b);
    g.Sb = __shfl(Sb_l, b);
    const int rb = __shfl(excl, b);        // batch row offset
    g.labidx = (b * TM + t) * SMAX + g.s;  // valid when s < SMAX
    g.val = (t < Tb) && (g.s <= g.Sb);
    const unsigned row = (unsigned)rb + (unsigned)t * (unsigned)(g.Sb + 1) + (unsigned)g.s;
    g.off = row * (unsigned)(VV * 4);
    // prefetch the label with the row loads (hides L2 latency)
    g.lab = (g.val && g.s < g.Sb) ? labels[b * SMAX + g.s] : -1;
  };

  auto issue = [&](const RowG& g, f32x4 (&x)[4]) {
    if (g.val) {
      const f32x4* rp = (const f32x4*)((const char*)acts + g.off) + lane;
      x[0] = __builtin_nontemporal_load(rp);
      x[1] = __builtin_nontemporal_load(rp + 64);
      x[2] = __builtin_nontemporal_load(rp + 128);
      x[3] = __builtin_nontemporal_load(rp + 192);
    }
  };

  auto computePair = [&](int cell0, const RowG (&g)[2], const f32x4 (&x0)[4],
                         const f32x4 (&x1)[4]) {
    float p0 = 0.0f, p1 = 0.0f;
    if (g[0].val) {
      #pragma unroll
      for (int j = 0; j < 4; ++j)
        p0 += __expf(x0[j].x) + __expf(x0[j].y) + __expf(x0[j].z) + __expf(x0[j].w);
    }
    if (g[1].val) {
      #pragma unroll
      for (int j = 0; j < 4; ++j)
        p1 += __expf(x1[j].x) + __expf(x1[j].y) + __expf(x1[j].z) + __expf(x1[j].w);
    }
    // two interleaved xor-butterflies: amortize the 6-step shuffle chain
    #pragma unroll
    for (int o = 1; o < 64; o <<= 1) {
      p0 += __shfl_xor(p0, o);
      p1 += __shfl_xor(p1, o);
    }

    #pragma unroll
    for (int k = 0; k < 2; ++k) {
      const int cell = cell0 + k;
      const RowG& gg = g[k];
      if (!gg.val) {
        if (lane == 0) {
          blank_lp[cell] = NEGF;
          if (gg.s < SMAX) label_lp[gg.labidx] = NEGF;
        }
        continue;
      }
      const float ps  = (k == 0) ? p0 : p1;
      const float lse = __logf(ps);
      if (gg.s < gg.Sb) {
        // wave-uniform label -> uniform (vec#, component, src lane) select
        const int f    = gg.lab >> 2;
        const int comp = gg.lab & 3;
        const int src  = f & 63;
        const int j    = f >> 6;
        f32x4 xx;
        if (k == 0) xx = (j == 0) ? x0[0] : (j == 1) ? x0[1] : (j == 2) ? x0[2] : x0[3];
        else        xx = (j == 0) ? x1[0] : (j == 1) ? x1[1] : (j == 2) ? x1[2] : x1[3];
        float v = (comp == 0) ? xx.x : (comp == 1) ? xx.y : (comp == 2) ? xx.z : xx.w;
        v = __shfl(v, src);
        if (lane == 0) label_lp[gg.labidx] = v - lse;
      } else if (gg.s < SMAX) {
        if (lane == 0) label_lp[gg.labidx] = NEGF;
      }
      if (lane == 0) {
        const float blank = (k == 0) ? x0[0].x : x1[0].x;  // elem 0 lives in lane 0
        blank_lp[cell] = blank - lse;
      }
    }
  };

  // ---- persistent ping-pong over pairs wave, wave+NWAVES, ... ----
  RowG gA[2], gB[2];
  f32x4 xA0[4], xA1[4], xB0[4], xB1[4];

  int pA = wave;
  if (pA >= NPAIRS) return;
  geo(2 * pA, gA[0]); geo(2 * pA + 1, gA[1]);
  issue(gA[0], xA0);  issue(gA[1], xA1);

  int pB = pA + NWAVES;
  for (;;) {
    const bool hB = (pB < NPAIRS);
    if (hB) {
      geo(2 * pB, gB[0]); geo(2 * pB + 1, gB[1]);
      issue(gB[0], xB0);  issue(gB[1], xB1);
    }
    computePair(2 * pA, gA, xA0, xA1);       // B's loads in flight
    if (!hB) break;

    const int pC = pB + NWAVES;
    const bool hC = (pC < NPAIRS);
    if (hC) {
      geo(2 * pC, gA[0]); geo(2 * pC + 1, gA[1]);
      issue(gA[0], xA0);  issue(gA[1], xA1);
    }
    computePair(2 * pB, gB, xB0, xB1);       // A's (next) loads in flight
    if (!hC) break;

    pA = pC;            // scalar-only rotation; buffers stay named
    pB = pC + NWAVES;
  }
}

// ---------------- Phase 2: alpha recurrence, one block per batch ----------
// 256 threads stage the 66 KB of log-probs into LDS, then wave 0 runs the
// T-step recurrence with in-register alpha: lane holds alpha[lane];
// alpha[64] replicated uniformly in a_hi. No __syncthreads in the time loop.
__global__ __launch_bounds__(256) void rnnt_alpha_kernel(
    const float* __restrict__ blank_lp, const float* __restrict__ label_lp,
    const int* __restrict__ Tlen, const int* __restrict__ Slen,
    float* __restrict__ out)
{
  __shared__ __align__(16) float sb[TM * (SMAX + 1)];  // 8320 floats
  __shared__ __align__(16) float sl[TM * SMAX];        // 8192 floats
  const int b = blockIdx.x;
  const int tid = threadIdx.x;

  const float* gb = blank_lp + (size_t)b * TM * (SMAX + 1);
  const float* gl = label_lp + (size_t)b * TM * SMAX;
  for (int i = tid * 4; i < TM * (SMAX + 1); i += 256 * 4)
    *(float4*)&sb[i] = *(const float4*)&gb[i];
  for (int i = tid * 4; i < TM * SMAX; i += 256 * 4)
    *(float4*)&sl[i] = *(const float4*)&gl[i];
  __syncthreads();
  if (tid >= 64) return;

  const int lane = tid;
  const int Tb = Tlen[b], Sb = Slen[b];
  float a    = (lane == 0) ? 0.0f : NEGF;  // alpha[lane], lane in [0,64)
  float a_hi = NEGF;                       // alpha[64], uniform on all lanes

  for (int t = 0; t < Tb; ++t) {
    const float blp      = sb[t * (SMAX + 1) + lane];
    const float llp_prev = (lane >= 1) ? sl[t * SMAX + lane - 1] : NEGF;
    const float blp64    = sb[t * (SMAX + 1) + 64];  // broadcast
    const float llp63    = sl[t * SMAX + 63];        // broadcast
    const float a_prev   = __shfl_up(a, 1);
    const float a63      = __shfl(a, 63);            // uniform
    const float newv = logaddexp_f(a + blp,
                                   (lane >= 1) ? (a_prev + llp_prev) : NEGF);
    const float new_hi = logaddexp_f(a_hi + blp64, a63 + llp63);
    a = newv;
    a_hi = new_hi;
  }

  const float via_shfl = __shfl(a, Sb & 63);  // executed by all lanes
  const float aS = (Sb < 64) ? via_shfl : a_hi;
  if (lane == 0) out[b] = -aS;
}

extern "C" void kernel_launch(void* const* d_in, const int* in_sizes, int n_in,
                              void* d_out, int out_size, void* d_ws, size_t ws_size,
                              hipStream_t stream) {
  const float* acts  = (const float*)d_in[0];
  const int* labels  = (const int*)d_in[1];
  const int* Tlen    = (const int*)d_in[2];
  const int* Slen    = (const int*)d_in[3];
  float* out = (float*)d_out;

  float* blank_lp = (float*)d_ws;                       // B*TM*(SMAX+1) floats
  float* label_lp = blank_lp + Bc * TM * (SMAX + 1);    // B*TM*SMAX floats

  rnnt_lp_kernel<<<LPBLOCKS, 256, 0, stream>>>(
      acts, labels, Tlen, Slen, blank_lp, label_lp);
  rnnt_alpha_kernel<<<Bc, 256, 0, stream>>>(
      blank_lp, label_lp, Tlen, Slen, out);
}